// Round 9
// baseline (117.804 us; speedup 1.0000x reference)
//
#include <hip/hip_runtime.h>

// RelativePositionEncoding (AF3-style), B=1, N=1024, C_Z=128.
// out[i,j,c] = W_pos[d_res][c] + W_tok[d_tok][c] + same_ent*w_ent[c] + W_chn[d_chain][c]
// W rows: [0:66) pos, [66:132) tok, 132 ent, [133:139) chain.  IN_DIM=139.
//
// R9 change vs R4 (101.4us best): GRID-STRIDE output ownership. Output is
// 524288 x 1KB chunks; wave g handles chunks g, g+8192, ... so the GPU's
// in-flight writes form ONE contiguous ~8MB window sweeping the buffer
// (mimics fillBufferAligned's address pattern). i decoded per-chunk from the
// same packed key LDS array as j. W in LDS, w_ent folded. Same occupancy as
// R4 (1024 thr, 2 blocks/CU, 32 waves/CU).

typedef float f4 __attribute__((ext_vector_type(4)));

constexpr int kN      = 1024;
constexpr int kRowF4  = 32;              // 128 floats = 32 x f4 per W row
constexpr int kWF4    = 139 * kRowF4;    // 4448 f4 elements
constexpr int kThr    = 1024;
constexpr int kBlocks = 512;
constexpr int kWaves  = kBlocks * (kThr / 64);        // 8192 waves
constexpr int kChunks = kN * kN * kRowF4 / 64;        // 524288 1KB chunks

__global__ __launch_bounds__(kThr) void relpos_kernel(
    const int* __restrict__ asym,
    const int* __restrict__ resi,
    const int* __restrict__ ent,
    const int* __restrict__ sym,
    const int* __restrict__ tok,
    const float* __restrict__ W,
    float* __restrict__ out)
{
    __shared__ f4  sW[kWF4];     // 71,168 B
    __shared__ int sKey[kN];     //  4,096 B

    const int tid = threadIdx.x;
    const f4* __restrict__ W4 = reinterpret_cast<const f4*>(W);

    // Stage W into LDS; fold w_ent (row 132) into chain rows 133..137
    // (same_ent <=> d_chain <= 4, so those rows always get +w_ent).
    for (int idx = tid; idx < kWF4; idx += kThr) {
        f4 v = W4[idx];
        if (idx >= 133 * kRowF4 && idx < 138 * kRowF4)
            v += W4[132 * kRowF4 + (idx & (kRowF4 - 1))];
        sW[idx] = v;
    }
    // Pack per-position indices: asym(2) | ent(2) | sym(2) | resi(9) | tok(10)
    {
        const int j = tid;
        sKey[j] = (asym[j] & 3) | ((ent[j] & 3) << 2) | ((sym[j] & 3) << 4)
                | ((resi[j] & 511) << 6) | ((tok[j] & 1023) << 15);
    }
    __syncthreads();

    const int lane = tid & 63;
    const int c4   = lane & 31;   // f4 column within the 128-wide channel dim
    const int jh   = lane >> 5;   // 0/1 : which j of the chunk's j-pair

    f4* __restrict__ out4 = reinterpret_cast<f4*>(out);

    const int gw = blockIdx.x * (kThr / 64) + (tid >> 6);

    #pragma unroll 2
    for (int c = gw; c < kChunks; c += kWaves) {
        const int i = c >> 9;                      // wave-uniform row
        const int j = ((c & 511) << 1) | jh;

        const int ki = sKey[i];                    // broadcast ds_read
        const int kj = sKey[j];

        const int ai =  ki        & 3, aj =  kj        & 3;
        const int ei = (ki >> 2)  & 3, ej = (kj >> 2)  & 3;
        const int si = (ki >> 4)  & 3, sj = (kj >> 4)  & 3;
        const int ri = (ki >> 6)  & 511, rj = (kj >> 6)  & 511;
        const int ti = (ki >> 15) & 1023, tj = (kj >> 15) & 1023;

        int dres = min(max(ri - rj + 32, 0), 64);
        if (ai != aj) dres = 65;
        int dtok = min(max(ti - tj + 32, 0), 64);
        if (!(ai == aj && ri == rj)) dtok = 65;
        int dchn = min(max(si - sj + 2, 0), 4);
        if (ei != ej) dchn = 5;

        const f4 v = sW[dres * kRowF4 + c4]
                   + sW[(66 + dtok) * kRowF4 + c4]
                   + sW[(133 + dchn) * kRowF4 + c4];

        out4[(size_t)c * 64 + lane] = v;
    }
}

extern "C" void kernel_launch(void* const* d_in, const int* in_sizes, int n_in,
                              void* d_out, int out_size, void* d_ws, size_t ws_size,
                              hipStream_t stream) {
    const int*   asym = (const int*)d_in[0];
    const int*   resi = (const int*)d_in[1];
    const int*   ent  = (const int*)d_in[2];
    const int*   sym  = (const int*)d_in[3];
    const int*   tok  = (const int*)d_in[4];
    const float* W    = (const float*)d_in[5];
    float*       out  = (float*)d_out;

    relpos_kernel<<<dim3(kBlocks), dim3(kThr), 0, stream>>>(asym, resi, ent, sym, tok, W, out);
}

// Round 10
// 99.797 us; speedup vs baseline: 1.1804x; 1.1804x over previous
//
#include <hip/hip_runtime.h>

// RelativePositionEncoding (AF3-style), B=1, N=1024, C_Z=128.
// out[i,j,c] = W_pos[d_res][c] + W_tok[d_tok][c] + same_ent*w_ent[c] + W_chn[d_chain][c]
// W rows: [0:66) pos, [66:132) tok, 132 ent, [133:139) chain.  IN_DIM=139.
//
// R10 change vs R4 (101.4us best): 4-wide BATCHED inner loop. Per batch:
// 4 key ds_reads back-to-back, 12 ds_read_b128 back-to-back, 8 f4 adds,
// then 4 wave-stores back-to-back with no LDS ops between — deepening the
// per-wave in-flight store queue (tests store-pipeline-depth hypothesis).
// Geometry/staging identical to R4: 512 blk x 1024 thr, W+keys in LDS.

typedef float f4 __attribute__((ext_vector_type(4)));

constexpr int kN     = 1024;
constexpr int kRowF4 = 32;             // 128 floats = 32 x f4 per W row
constexpr int kWF4   = 139 * kRowF4;   // 4448 f4 elements

__global__ __launch_bounds__(1024) void relpos_kernel(
    const int* __restrict__ asym,
    const int* __restrict__ resi,
    const int* __restrict__ ent,
    const int* __restrict__ sym,
    const int* __restrict__ tok,
    const float* __restrict__ W,
    float* __restrict__ out)
{
    __shared__ f4  sW[kWF4];     // 71,168 B
    __shared__ int sKey[kN];     //  4,096 B

    const int tid = threadIdx.x;
    const f4* __restrict__ W4 = reinterpret_cast<const f4*>(W);

    // Stage W into LDS; fold w_ent (row 132) into chain rows 133..137
    // (same_ent <=> d_chain <= 4, so those rows always get +w_ent).
    for (int idx = tid; idx < kWF4; idx += 1024) {
        f4 v = W4[idx];
        if (idx >= 133 * kRowF4 && idx < 138 * kRowF4)
            v += W4[132 * kRowF4 + (idx & (kRowF4 - 1))];
        sW[idx] = v;
    }
    // Pack per-j indices: asym(2) | ent(2) | sym(2) | resi(9) | tok(10)
    {
        const int j = tid;
        sKey[j] = (asym[j] & 3) | ((ent[j] & 3) << 2) | ((sym[j] & 3) << 4)
                | ((resi[j] & 511) << 6) | ((tok[j] & 1023) << 15);
    }
    __syncthreads();

    const int c4 = tid & 31;   // f4 column within the 128-wide channel dim
    const int jg = tid >> 5;   // 0..31 : j sub-index per iteration

    f4* __restrict__ out4 = reinterpret_cast<f4*>(out);

    const int i0 = blockIdx.x * 2;
    for (int ii = 0; ii < 2; ++ii) {
        const int i = i0 + ii;
        // Row-i values are block-uniform -> scalar loads.
        const int ai = asym[i], ri = resi[i], ei = ent[i], si = sym[i], ti = tok[i];
        f4* __restrict__ orow = out4 + (size_t)i * kN * kRowF4 + c4;

        #pragma unroll 1
        for (int it4 = 0; it4 < kN / 128; ++it4) {
            const int jb = it4 * 128 + jg;

            // Phase 1: 4 independent key reads.
            int kk[4];
            #pragma unroll
            for (int u = 0; u < 4; ++u) kk[u] = sKey[jb + u * 32];

            // Phase 2: decode + 12 row reads + adds (compiler interleaves).
            f4 v[4];
            #pragma unroll
            for (int u = 0; u < 4; ++u) {
                const int k  = kk[u];
                const int aj =  k        & 3;
                const int ej = (k >> 2)  & 3;
                const int sj = (k >> 4)  & 3;
                const int rj = (k >> 6)  & 511;
                const int tj = (k >> 15) & 1023;

                int dres = min(max(ri - rj + 32, 0), 64);
                if (ai != aj) dres = 65;
                int dtok = min(max(ti - tj + 32, 0), 64);
                if (!(ai == aj && ri == rj)) dtok = 65;
                int dchn = min(max(si - sj + 2, 0), 4);
                if (ei != ej) dchn = 5;

                v[u] = sW[dres * kRowF4 + c4]
                     + sW[(66 + dtok) * kRowF4 + c4]
                     + sW[(133 + dchn) * kRowF4 + c4];
            }

            // Phase 3: 4 stores back-to-back, no LDS ops between.
            #pragma unroll
            for (int u = 0; u < 4; ++u)
                orow[(size_t)(jb + u * 32) * kRowF4] = v[u];
        }
    }
}

extern "C" void kernel_launch(void* const* d_in, const int* in_sizes, int n_in,
                              void* d_out, int out_size, void* d_ws, size_t ws_size,
                              hipStream_t stream) {
    const int*   asym = (const int*)d_in[0];
    const int*   resi = (const int*)d_in[1];
    const int*   ent  = (const int*)d_in[2];
    const int*   sym  = (const int*)d_in[3];
    const int*   tok  = (const int*)d_in[4];
    const float* W    = (const float*)d_in[5];
    float*       out  = (float*)d_out;

    relpos_kernel<<<dim3(kN / 2), dim3(1024), 0, stream>>>(asym, resi, ent, sym, tok, W, out);
}